// Round 3
// baseline (343.581 us; speedup 1.0000x reference)
//
#include <hip/hip_runtime.h>
#include <math.h>

#define BB 8
#define LL 1024
#define DD 1024
#define KD 1024   // GEMM K depth (token-space GEMMs)
#define NM 32     // complex modes per channel
#define NCH 16    // chunks over L
#define CL 64     // chunk length (NCH*CL == LL)
#define NTOK (BB * LL)
#define GSMEM 147456  // 3 * (256*64 + 128*64) * 2B = 144 KiB

typedef __bf16 bf16_t;
typedef __bf16 bf16x8 __attribute__((ext_vector_type(8)));
typedef __bf16 bf16x4 __attribute__((ext_vector_type(4)));
typedef float  f32x4  __attribute__((ext_vector_type(4)));

__device__ __forceinline__ float gelu_f(float z)
{
    float t = fmaf(0.044715f * z * z, z, z);
    return z / (1.f + expf(-1.5957691216f * t));
}

// ---------------- fused fp32 -> bf16 converts (x, in_W, gluW, outW) -----------
__global__ __launch_bounds__(256)
void f2b_all_kernel(const float* __restrict__ x,    bf16_t* __restrict__ xb,
                    const float* __restrict__ w0,   bf16_t* __restrict__ d0,
                    const float* __restrict__ w1,   bf16_t* __restrict__ d1,
                    const float* __restrict__ w2,   bf16_t* __restrict__ d2)
{
    int b = blockIdx.x;
    const float* s; bf16_t* d; int base;
    if (b < 8192)       { s = x;  d = xb; base = b; }
    else if (b < 9216)  { s = w0; d = d0; base = b - 8192; }
    else if (b < 11264) { s = w1; d = d1; base = b - 9216; }
    else                { s = w2; d = d2; base = b - 11264; }
    int i = (base * 256 + threadIdx.x) * 4;
    float4 f = *(const float4*)(s + i);
    bf16x4 o = { (bf16_t)f.x, (bf16_t)f.y, (bf16_t)f.z, (bf16_t)f.w };
    *(bf16x4*)(d + i) = o;
}

// =============================================================================
// 256x128 GEMM, BK=64, 8 waves (4M x 2N, each wave 64x64 C), m201-style
// fine-phase schedule. __launch_bounds__(512,1): LDS (144 KiB) already limits
// to 1 block/CU, so min-waves=1 unlocks the 256-VGPR budget (the (512,2) cap
// at 128 VGPR caused 252 MB/dispatch of scratch spill in r2 -- MfmaUtil 0.5%).
//   per K-tile: 2 phases (kk=0,1). Each phase:
//     {8x ds_read_b128 (XOR-swizzled) | issue 1 staging chunk (3 insts)}
//     s_barrier ; setprio(1) ; 16x MFMA ; setprio(0) ; s_barrier
//   3 LDS tile-buffers. Chunks issued 2 K-tiles ahead. Tile-boundary wait =
//   counted vmcnt(6) (next tile's 6 loads stay in flight); drains only at tail.
//   MODE 0: bf16 out = acc + bias[m]                    (in-proj, ch-major)
//   MODE 1: K run twice (a-rows then g-rows of glu_W);
//           bf16 out = (accA+ba)*sigmoid(accG+bg)       (GLU fused)
//   MODE 2: f32  out = acc + bias[n] + res[m,n]         (out-proj + residual)
// Swizzle (verified r1, conflicts=0): logical (row,col) stored at
//   col ^ ((row&7)<<3); global_load_lds dest linear, SOURCE pre-inverse-swz.
// =============================================================================
#define GLL(gp, lp) __builtin_amdgcn_global_load_lds( \
    (const __attribute__((address_space(1))) void*)(gp), \
    (__attribute__((address_space(3))) void*)(lp), 16, 0, 0)

// chunk h of a K-tile: A rows [h*128, h*128+128) + B rows [h*64, h*64+64)
// = 3 global_load_lds per thread (A:2, B:1)
__device__ __forceinline__ void stage_chunk(const bf16_t* __restrict__ Ag,
                                            const bf16_t* __restrict__ Bg,
                                            bf16_t* Asb, bf16_t* Bsb,
                                            int h, int tid)
{
    #pragma unroll
    for (int q = 0; q < 2; ++q) {
        int e = (h * 2 + q) * 512 + tid;          // 0..2047  (A: 256 rows x 64)
        int row = e >> 3, c8 = (e & 7) << 3;
        int sc = c8 ^ ((row & 7) << 3);
        GLL(Ag + (size_t)row * KD + sc, Asb + e * 8);
    }
    {
        int e = h * 512 + tid;                    // 0..1023  (B: 128 rows x 64)
        int row = e >> 3, c8 = (e & 7) << 3;
        int sc = c8 ^ ((row & 7) << 3);
        GLL(Bg + (size_t)row * KD + sc, Bsb + e * 8);
    }
}

template<int MODE>
__global__ __launch_bounds__(512, 1)
void gemm8p_kernel(const bf16_t* __restrict__ A, const bf16_t* __restrict__ B,
                   const float* __restrict__ bias, const float* __restrict__ res,
                   void* __restrict__ outp)
{
    extern __shared__ __align__(16) bf16_t lds[];
    bf16_t* As = lds;                 // 3 x 16384 elems (256x64)
    bf16_t* Bs = lds + 3 * 16384;     // 3 x  8192 elems (128x64)

    const int tid = threadIdx.x;
    const int lane = tid & 63, w = tid >> 6;
    const int wy = w >> 1, wx = w & 1;           // 4M x 2N waves
    const int lm = lane & 15, ks = (lane >> 4) << 3;

    // flatten + XCD-contiguous swizzle (nwg == 256 in all modes, 256%8==0)
    const int nbx = gridDim.x;
    int bid = blockIdx.y * nbx + blockIdx.x;
    const int cpx = (gridDim.x * gridDim.y) >> 3;
    bid = (bid & 7) * cpx + (bid >> 3);
    const int by = bid / nbx, bx = bid % nbx;
    const int m0 = by * 256, n0 = bx * 128;

    const bf16_t* Ag = A + (size_t)m0 * KD;
    const bf16_t* B0 = B + (size_t)n0 * KD;
    const bf16_t* B1 = (MODE == 1) ? B + (size_t)(1024 + n0) * KD : B0;
    const int NT = (MODE == 1) ? 32 : 16;

    f32x4 acc[4][4]  = {};
    f32x4 acc2[4][4] = {};   // g-accumulator (MODE 1 only; DCE'd otherwise)

    // prologue: tiles 0,1 -> bufs 0,1 (12 insts); wait tile0 (leave tile1's 6)
    stage_chunk(Ag,      B0,      As,         Bs,        0, tid);
    stage_chunk(Ag,      B0,      As,         Bs,        1, tid);
    stage_chunk(Ag + 64, B0 + 64, As + 16384, Bs + 8192, 0, tid);
    stage_chunk(Ag + 64, B0 + 64, As + 16384, Bs + 8192, 1, tid);
    asm volatile("s_waitcnt vmcnt(6)" ::: "memory");
    __builtin_amdgcn_s_barrier();

    int q = 0, q2 = 2;   // buffer indices for tile t and tile t+2 (mod 3)
    #pragma unroll 1
    for (int t = 0; t < NT; ++t) {
        const bf16_t* Asb = As + q * 16384;
        const bf16_t* Bsb = Bs + q * 8192;
        const int t2 = t + 2;
        const bool st = (t2 < NT);
        const bf16_t* Ag2 = Ag;
        const bf16_t* Bg2 = B0;
        bf16_t* As2 = As; bf16_t* Bs2 = Bs;
        if (st) {
            Ag2 = Ag + (t2 & 15) * 64;
            Bg2 = ((MODE == 1 && t2 >= 16) ? B1 : B0) + (t2 & 15) * 64;
            As2 = As + q2 * 16384; Bs2 = Bs + q2 * 8192;
        }

        auto tile_body = [&](f32x4 (&ac)[4][4]) {
            #pragma unroll
            for (int kk = 0; kk < 2; ++kk) {
                bf16x8 af[4], bfr[4];
                const int col = kk * 32 + ks;
                #pragma unroll
                for (int i = 0; i < 4; ++i) {
                    int row = wy * 64 + i * 16 + lm;
                    af[i] = *(const bf16x8*)(Asb + row * 64
                                             + (col ^ ((row & 7) << 3)));
                }
                #pragma unroll
                for (int j = 0; j < 4; ++j) {
                    int row = wx * 64 + j * 16 + lm;
                    bfr[j] = *(const bf16x8*)(Bsb + row * 64
                                              + (col ^ ((row & 7) << 3)));
                }
                if (st) stage_chunk(Ag2, Bg2, As2, Bs2, kk, tid);
                __builtin_amdgcn_s_barrier();
                __builtin_amdgcn_s_setprio(1);
                #pragma unroll
                for (int i = 0; i < 4; ++i)
                    #pragma unroll
                    for (int j = 0; j < 4; ++j)
                        ac[i][j] = __builtin_amdgcn_mfma_f32_16x16x32_bf16(
                                       af[i], bfr[j], ac[i][j], 0, 0, 0);
                __builtin_amdgcn_s_setprio(0);
                if (kk == 1 && t + 1 < NT) {
                    // tile-boundary wait: t+1 landed; t+2's 6 stay in flight
                    if (st) asm volatile("s_waitcnt vmcnt(6)" ::: "memory");
                    else    asm volatile("s_waitcnt vmcnt(0)" ::: "memory");
                }
                __builtin_amdgcn_s_barrier();
            }
        };
        if (MODE == 1 && t >= 16) tile_body(acc2); else tile_body(acc);
        q = (q == 2) ? 0 : q + 1;
        q2 = (q2 == 2) ? 0 : q2 + 1;
    }

    // ---- epilogue ----
    const int r4 = (lane >> 4) << 2;
    #pragma unroll
    for (int i = 0; i < 4; ++i)
        #pragma unroll
        for (int r = 0; r < 4; ++r) {
            int m = m0 + wy * 64 + i * 16 + r4 + r;
            #pragma unroll
            for (int j = 0; j < 4; ++j) {
                int n = n0 + wx * 64 + j * 16 + lm;
                if (MODE == 0) {
                    ((bf16_t*)outp)[(size_t)m * 8192 + n] =
                        (bf16_t)(acc[i][j][r] + bias[m]);
                } else if (MODE == 1) {
                    float a = acc[i][j][r]  + bias[n];
                    float g = acc2[i][j][r] + bias[1024 + n];
                    ((bf16_t*)outp)[(size_t)m * 1024 + n] =
                        (bf16_t)(a / (1.f + expf(-g)));
                } else {
                    ((float*)outp)[(size_t)m * 1024 + n] =
                        acc[i][j][r] + bias[n] + res[(size_t)m * 1024 + n];
                }
            }
        }
}

// ---------------- genV + genTP merged (block-uniform branch) ------------------
__global__ __launch_bounds__(64)
void genVTP_kernel(const float* __restrict__ log_dt, const float* __restrict__ lar,
                   const float* __restrict__ aim, const float* __restrict__ Cp,
                   const float* __restrict__ dskip,
                   bf16_t* __restrict__ V, bf16_t* __restrict__ TP)
{
    const int tid = threadIdx.x;
    if (blockIdx.x < DD / 2) {
        const int h = blockIdx.x * 2 + (tid >> 5);
        const int n = tid & 31;
        const float dt = expf(log_dt[h]);
        const float ardt = -expf(lar[h * NM + n]) * dt;
        const float aidt = aim[h * NM + n] * dt;
        float sn, cs;
        sincosf(aidt, &sn, &cs);
        float er = expf(ardt);
        float wr = er * cs, wi = er * sn;
        float inv = 1.f / fmaf(wr, wr, wi * wi);
        float vr = wr * inv, vi = -wi * inv;      // w^-1
        sincosf(63.f * aidt, &sn, &cs);
        er = expf(63.f * ardt);
        float pr = er * cs, pi = er * sn;         // w^63
        bf16_t* rowr = V + ((size_t)h * 64 + 2 * n) * 64;
        bf16_t* rowi = rowr + 64;
        #pragma unroll
        for (int c8 = 0; c8 < 8; ++c8) {
            bf16x8 rr, ri;
            #pragma unroll
            for (int e = 0; e < 8; ++e) {
                rr[e] = (bf16_t)pr; ri[e] = (bf16_t)pi;
                float t = fmaf(pr, vr, -pi * vi);
                pi = fmaf(pr, vi, pi * vr);
                pr = t;
            }
            *(bf16x8*)(rowr + c8 * 8) = rr;
            *(bf16x8*)(rowi + c8 * 8) = ri;
        }
        return;
    }
    // ---- TP branch ----
    __shared__ float ardt_s[NM], aidt_s[NM], cr_s[NM], ci_s[NM], K_s[CL];
    const int h = blockIdx.x - DD / 2;
    const float dt = expf(log_dt[h]);
    if (tid < NM) {
        int n = tid;
        float ar = -expf(lar[h * NM + n]);
        float ai = aim[h * NM + n];
        float sn, cs;
        sincosf(ai * dt, &sn, &cs);
        float er = expf(ar * dt);
        float wrr = er * cs, wii = er * sn;
        float Crr = Cp[(h * NM + n) * 2 + 0];
        float Cii = Cp[(h * NM + n) * 2 + 1];
        float nr = fmaf(Crr, wrr - 1.f, -Cii * wii);
        float ni = fmaf(Crr, wii, Cii * (wrr - 1.f));
        float inv = 2.f / fmaf(ar, ar, ai * ai);
        cr_s[n] = fmaf(nr, ar, ni * ai) * inv;
        ci_s[n] = fmaf(ni, ar, -nr * ai) * inv;
        ardt_s[n] = ar * dt;
        aidt_s[n] = ai * dt;
    }
    __syncthreads();
    {   // K[d] = sum_n cr*Re(w^d) - ci*Im(w^d);  K[0] += D_skip
        float d = (float)tid;
        float kv = (tid == 0) ? dskip[h] : 0.f;
        #pragma unroll 8
        for (int n = 0; n < NM; ++n) {
            float sn, cs;
            sincosf(aidt_s[n] * d, &sn, &cs);
            float e = expf(ardt_s[n] * d);
            kv = fmaf(cr_s[n], e * cs, kv);
            kv = fmaf(-ci_s[n], e * sn, kv);
        }
        K_s[tid] = kv;
    }
    __syncthreads();
    const int i = tid;
    bf16_t* row = TP + ((size_t)h * CL + i) * 128;
    #pragma unroll
    for (int c8 = 0; c8 < 8; ++c8) {
        bf16x8 v;
        #pragma unroll
        for (int e = 0; e < 8; ++e) {
            int l = c8 * 8 + e;
            v[e] = (l <= i) ? (bf16_t)K_s[i - l] : (bf16_t)0.f;
        }
        *(bf16x8*)(row + c8 * 8) = v;
    }
    const float fi = (float)(i + 1);
    #pragma unroll
    for (int c8 = 0; c8 < 8; ++c8) {
        bf16x8 v;
        #pragma unroll
        for (int q = 0; q < 4; ++q) {
            int n = c8 * 4 + q;
            float sn, cs;
            sincosf(aidt_s[n] * fi, &sn, &cs);
            float e = expf(ardt_s[n] * fi);
            float Wr = e * cs, Wi = e * sn;
            v[2 * q]     = (bf16_t)(fmaf(cr_s[n], Wr, -ci_s[n] * Wi));
            v[2 * q + 1] = (bf16_t)(-fmaf(cr_s[n], Wi, ci_s[n] * Wr));
        }
        *(bf16x8*)(row + 64 + c8 * 8) = v;
    }
}

// ---------------- fused SSM: S=U@V^T -> scan (LDS) -> Y=[U|Sc]@TP^T, gelu -----
__global__ __launch_bounds__(256)
void ssm_fused_kernel(const bf16_t* __restrict__ u_ch, const bf16_t* __restrict__ V,
                      const bf16_t* __restrict__ TP,
                      const float* __restrict__ log_dt, const float* __restrict__ lar,
                      const float* __restrict__ aim, bf16_t* __restrict__ y_bi)
{
    __shared__ float  Sbc_s[128 * 64];
    __shared__ bf16_t Sc_s[128 * 64];
    const int h = blockIdx.x;
    const int tid = threadIdx.x;
    const int lane = tid & 63, w = tid >> 6;
    const int lm = lane & 15, ks = (lane >> 4) << 3;
    const bf16_t* U   = u_ch + (size_t)h * 8192;  // [128 batch][64 l]
    const bf16_t* Vh  = V    + (size_t)h * 4096;  // [64 comp][64 l]
    const bf16_t* TPh = TP   + (size_t)h * 8192;  // [64 i][128 k]

    bf16x8 af_u[2][2];
    #pragma unroll
    for (int im = 0; im < 2; ++im)
        #pragma unroll
        for (int kk = 0; kk < 2; ++kk)
            af_u[im][kk] = *(const bf16x8*)(U + (((w << 1) + im) * 16 + lm) * 64
                                            + kk * 32 + ks);

    // ---- G1: chunk-local end states ----
    f32x4 acc1[2][4] = {};
    #pragma unroll
    for (int kk = 0; kk < 2; ++kk) {
        bf16x8 bfr[4];
        #pragma unroll
        for (int jn = 0; jn < 4; ++jn)
            bfr[jn] = *(const bf16x8*)(Vh + (jn * 16 + lm) * 64 + kk * 32 + ks);
        #pragma unroll
        for (int im = 0; im < 2; ++im)
            #pragma unroll
            for (int jn = 0; jn < 4; ++jn)
                acc1[im][jn] = __builtin_amdgcn_mfma_f32_16x16x32_bf16(
                                   af_u[im][kk], bfr[jn], acc1[im][jn], 0, 0, 0);
    }
    const int r4 = (lane >> 4) << 2;
    #pragma unroll
    for (int im = 0; im < 2; ++im)
        #pragma unroll
        for (int jn = 0; jn < 4; ++jn)
            #pragma unroll
            for (int r = 0; r < 4; ++r)
                Sbc_s[(((w << 1) + im) * 16 + r4 + r) * 64 + jn * 16 + lm]
                    = acc1[im][jn][r];
    __syncthreads();

    // ---- scan over chunks: thread t -> (b = t>>5, n = t&31) ----
    {
        const int b = tid >> 5, n = tid & 31;
        const float dtv = expf(log_dt[h]);
        const float ardt = -expf(lar[h * NM + n]) * dtv;
        const float aidt = aim[h * NM + n] * dtv;
        float sn, cs;
        sincosf(64.f * aidt, &sn, &cs);
        float er = expf(64.f * ardt);
        const float gr = er * cs, gi = er * sn;   // w^CL
        float sr = 0.f, si = 0.f;
        for (int c = 0; c < NCH; ++c) {
            int idx = (b * 16 + c) * 64 + 2 * n;
            float lr = Sbc_s[idx], li = Sbc_s[idx + 1];
            Sc_s[idx]     = (bf16_t)sr;
            Sc_s[idx + 1] = (bf16_t)si;
            float t0 = fmaf(gr, sr, fmaf(-gi, si, lr));
            si = fmaf(gr, si, fmaf(gi, sr, li));
            sr = t0;
        }
    }
    __syncthreads();

    // ---- G3: Y = [U | Sc] @ TP^T, gelu ----
    f32x4 acc2[2][4] = {};
    #pragma unroll
    for (int kk = 0; kk < 4; ++kk) {
        bf16x8 af[2], bfr[4];
        #pragma unroll
        for (int im = 0; im < 2; ++im) {
            if (kk < 2)
                af[im] = af_u[im][kk];
            else
                af[im] = *(bf16x8*)&Sc_s[(((w << 1) + im) * 16 + lm) * 64
                                         + (kk - 2) * 32 + ks];
        }
        #pragma unroll
        for (int jn = 0; jn < 4; ++jn)
            bfr[jn] = *(const bf16x8*)(TPh + (jn * 16 + lm) * 128 + kk * 32 + ks);
        #pragma unroll
        for (int im = 0; im < 2; ++im)
            #pragma unroll
            for (int jn = 0; jn < 4; ++jn)
                acc2[im][jn] = __builtin_amdgcn_mfma_f32_16x16x32_bf16(
                                   af[im], bfr[jn], acc2[im][jn], 0, 0, 0);
    }
    bf16_t* out = y_bi + (size_t)h * 8192;        // [128 batch][64 i]
    #pragma unroll
    for (int im = 0; im < 2; ++im)
        #pragma unroll
        for (int jn = 0; jn < 4; ++jn)
            #pragma unroll
            for (int r = 0; r < 4; ++r) {
                int batch = ((w << 1) + im) * 16 + r4 + r;
                int i = jn * 16 + lm;
                out[batch * 64 + i] = (bf16_t)gelu_f(acc2[im][jn][r]);
            }
}

// ---------------- 64x64 bf16 tile transpose: dst[c][r] = src[r][c] ------------
__global__ __launch_bounds__(256)
void transpose_kernel(const bf16_t* __restrict__ src, bf16_t* __restrict__ dst,
                      int src_rows, int src_cols)
{
    __shared__ unsigned short tile[64][68];
    const int tid = threadIdx.x;
    const int c0 = blockIdx.x << 6, r0 = blockIdx.y << 6;
    const int r = tid >> 4, c4 = (tid & 15) << 2;
    #pragma unroll
    for (int p = 0; p < 4; ++p) {
        int rr = p * 16 + r;
        ushort4 v = *(const ushort4*)((const unsigned short*)src +
                                      (size_t)(r0 + rr) * src_cols + c0 + c4);
        *(ushort4*)&tile[rr][c4] = v;
    }
    __syncthreads();
    #pragma unroll
    for (int p = 0; p < 4; ++p) {
        int rr = p * 16 + r;
        ushort4 v;
        v.x = tile[c4 + 0][rr];
        v.y = tile[c4 + 1][rr];
        v.z = tile[c4 + 2][rr];
        v.w = tile[c4 + 3][rr];
        *(ushort4*)((unsigned short*)dst + (size_t)(c0 + rr) * src_rows + r0 + c4) = v;
    }
}

extern "C" void kernel_launch(void* const* d_in, const int* in_sizes, int n_in,
                              void* d_out, int out_size, void* d_ws, size_t ws_size,
                              hipStream_t stream)
{
    (void)in_sizes; (void)n_in; (void)out_size; (void)ws_size;
    const float* x      = (const float*)d_in[0];
    const float* in_W   = (const float*)d_in[1];
    const float* in_b   = (const float*)d_in[2];
    const float* log_dt = (const float*)d_in[3];
    const float* Cp     = (const float*)d_in[4];
    const float* lar    = (const float*)d_in[5];
    const float* aim    = (const float*)d_in[6];
    const float* dsk    = (const float*)d_in[7];
    const float* gluW   = (const float*)d_in[8];
    const float* glub   = (const float*)d_in[9];
    const float* outW   = (const float*)d_in[10];
    const float* outb   = (const float*)d_in[11];

    // ws layout:
    //  [0,16M):  xb -> TP (after in-proj) -> y_tok (after ssm)
    //  [16,32M): V (dead after ssm) -> vb (GLU-fused output)
    //  [32,48M): u_ch (bf16, channel-major)
    //  [48M..):  wbin 2M | wbglu 4M | wbout 2M
    char* ws = (char*)d_ws;
    bf16_t* xb    = (bf16_t*)(ws);
    bf16_t* TP    = (bf16_t*)(ws);
    bf16_t* y_tok = (bf16_t*)(ws);
    bf16_t* V     = (bf16_t*)(ws + 16777216);
    bf16_t* vb    = (bf16_t*)(ws + 16777216);
    bf16_t* u_ch  = (bf16_t*)(ws + 33554432);
    bf16_t* wbin  = (bf16_t*)(ws + 50331648);
    bf16_t* wbglu = (bf16_t*)(ws + 52428800);
    bf16_t* wbout = (bf16_t*)(ws + 56623104);
    bf16_t* y_bi  = (bf16_t*)d_out;

    static bool s_attr = false;
    if (!s_attr) {
        hipFuncSetAttribute((const void*)gemm8p_kernel<0>,
                            hipFuncAttributeMaxDynamicSharedMemorySize, GSMEM);
        hipFuncSetAttribute((const void*)gemm8p_kernel<1>,
                            hipFuncAttributeMaxDynamicSharedMemorySize, GSMEM);
        hipFuncSetAttribute((const void*)gemm8p_kernel<2>,
                            hipFuncAttributeMaxDynamicSharedMemorySize, GSMEM);
        s_attr = true;
    }

    f2b_all_kernel<<<dim3(12288), dim3(256), 0, stream>>>(
        x, xb, in_W, wbin, gluW, wbglu, outW, wbout);

    // in-proj, channel-major output: u_ch[h][token]  (M=1024 ch, N=8192 tok)
    gemm8p_kernel<0><<<dim3(NTOK / 128, DD / 256), dim3(512), GSMEM, stream>>>(
        wbin, xb, in_b, nullptr, u_ch);

    // SSM: param tables, then fused per-channel (G1 -> scan -> G3)
    genVTP_kernel<<<dim3(DD / 2 + DD), dim3(64), 0, stream>>>(
        log_dt, lar, aim, Cp, dsk, V, TP);
    ssm_fused_kernel<<<dim3(DD), dim3(256), 0, stream>>>(
        u_ch, V, TP, log_dt, lar, aim, y_bi);

    // back to token-major, then fused GLU GEMM (a & g passes + sigmoid combine)
    transpose_kernel<<<dim3(NTOK / 64, DD / 64), dim3(256), 0, stream>>>(y_bi, y_tok, DD, NTOK);
    gemm8p_kernel<1><<<dim3(1024 / 128, NTOK / 256), dim3(512), GSMEM, stream>>>(
        y_tok, wbglu, glub, nullptr, vb);

    // out-proj + residual
    gemm8p_kernel<2><<<dim3(DD / 128, NTOK / 256), dim3(512), GSMEM, stream>>>(
        vb, wbout, outb, x, d_out);
}

// Round 4
// 290.803 us; speedup vs baseline: 1.1815x; 1.1815x over previous
//
#include <hip/hip_runtime.h>
#include <math.h>

#define BB 8
#define LL 1024
#define DD 1024
#define KD 1024   // GEMM K depth (token-space GEMMs)
#define NM 32     // complex modes per channel
#define NCH 16    // chunks over L
#define CL 64     // chunk length (NCH*CL == LL)
#define NTOK (BB * LL)

typedef __bf16 bf16_t;
typedef __bf16 bf16x8 __attribute__((ext_vector_type(8)));
typedef __bf16 bf16x4 __attribute__((ext_vector_type(4)));
typedef float  f32x4  __attribute__((ext_vector_type(4)));

__device__ __forceinline__ float gelu_f(float z)
{
    float t = fmaf(0.044715f * z * z, z, z);
    return z / (1.f + expf(-1.5957691216f * t));
}

// ---------------- fused fp32 -> bf16 converts (x, in_W, gluW, outW) -----------
__global__ __launch_bounds__(256)
void f2b_all_kernel(const float* __restrict__ x,    bf16_t* __restrict__ xb,
                    const float* __restrict__ w0,   bf16_t* __restrict__ d0,
                    const float* __restrict__ w1,   bf16_t* __restrict__ d1,
                    const float* __restrict__ w2,   bf16_t* __restrict__ d2)
{
    int b = blockIdx.x;
    const float* s; bf16_t* d; int base;
    if (b < 8192)       { s = x;  d = xb; base = b; }
    else if (b < 9216)  { s = w0; d = d0; base = b - 8192; }
    else if (b < 11264) { s = w1; d = d1; base = b - 9216; }
    else                { s = w2; d = d2; base = b - 11264; }
    int i = (base * 256 + threadIdx.x) * 4;
    float4 f = *(const float4*)(s + i);
    bf16x4 o = { (bf16_t)f.x, (bf16_t)f.y, (bf16_t)f.z, (bf16_t)f.w };
    *(bf16x4*)(d + i) = o;
}

// =============================================================================
// 128x128 GEMM, BK=64, 4 waves (2x2), 256 threads -- r0's verified structure
// plus two surgical changes:
//  (a) granule-XOR LDS swizzle: [128][64] bf16 tile; 16B granule g of row r
//      stored at g ^ (r&7). Un-swizzled this read pattern is a 16-way bank
//      conflict (4.19M/dispatch in r0); swizzled it is 2-way = free (m136).
//      global_load_lds dest stays linear; the GLOBAL source col is
//      pre-inverse-swizzled (involution), verified in r1 (conflicts -> 0).
//  (b) minimum 2-phase double-buffer (T3-min): stage(t+1) issued BEFORE
//      compute(t); one __syncthreads (vmcnt-drain + barrier) per K-tile.
// MODE 0: bf16 out = acc + bias[m]            (in-proj, channel-major out)
// MODE 1: bf16 out = acc + bias[n]            (GLU z)
// MODE 2: f32  out = acc + bias[n] + res[m,n] (out-proj + residual)
// =============================================================================
#define GLL(gp, lp) __builtin_amdgcn_global_load_lds( \
    (const __attribute__((address_space(1))) void*)(gp), \
    (__attribute__((address_space(3))) void*)(lp), 16, 0, 0)

// one K-tile: A 128 rows x 64 cols + B 128 rows x 64 cols, 4+4 loads/thread
__device__ __forceinline__ void stage_tile(const bf16_t* __restrict__ Ag,
                                           const bf16_t* __restrict__ Bg,
                                           bf16_t* Asb, bf16_t* Bsb, int tid)
{
    #pragma unroll
    for (int p = 0; p < 4; ++p) {
        int e = p * 256 + tid;                    // 0..1023 (128 rows x 8 gran)
        int row = e >> 3, sc = ((e & 7) ^ (row & 7)) << 3;
        GLL(Ag + (size_t)row * KD + sc, Asb + e * 8);
    }
    #pragma unroll
    for (int p = 0; p < 4; ++p) {
        int e = p * 256 + tid;
        int row = e >> 3, sc = ((e & 7) ^ (row & 7)) << 3;
        GLL(Bg + (size_t)row * KD + sc, Bsb + e * 8);
    }
}

template<int MODE>
__global__ __launch_bounds__(256, 2)
void gemm_db_kernel(const bf16_t* __restrict__ A, const bf16_t* __restrict__ B,
                    const float* __restrict__ bias, const float* __restrict__ res,
                    void* __restrict__ outp, int ldo)
{
    __shared__ bf16_t As[2][128 * 64];
    __shared__ bf16_t Bs[2][128 * 64];
    const int tid = threadIdx.x;
    const int lane = tid & 63, w = tid >> 6;
    const int wy = w >> 1, wx = w & 1;
    const int m0 = blockIdx.y << 7, n0 = blockIdx.x << 7;
    const bf16_t* Ag = A + (size_t)m0 * KD;
    const bf16_t* Bg = B + (size_t)n0 * KD;
    f32x4 acc[4][4] = {};
    const int lm = lane & 15;
    const int qq = lane >> 4;                     // quarter-wave index

    stage_tile(Ag, Bg, As[0], Bs[0], tid);
    __syncthreads();

    int buf = 0;
    #pragma unroll 1
    for (int t = 0; t < 16; ++t) {
        if (t + 1 < 16)
            stage_tile(Ag + (t + 1) * 64, Bg + (t + 1) * 64,
                       As[buf ^ 1], Bs[buf ^ 1], tid);
        #pragma unroll
        for (int kk = 0; kk < 2; ++kk) {
            bf16x8 af[4], bfr[4];
            const int g = (kk << 2) + qq;         // logical 16B granule 0..7
            #pragma unroll
            for (int i = 0; i < 4; ++i) {
                int row = (wy << 6) + (i << 4) + lm;
                af[i] = *(const bf16x8*)&As[buf][row * 64 + ((g ^ (row & 7)) << 3)];
            }
            #pragma unroll
            for (int j = 0; j < 4; ++j) {
                int row = (wx << 6) + (j << 4) + lm;
                bfr[j] = *(const bf16x8*)&Bs[buf][row * 64 + ((g ^ (row & 7)) << 3)];
            }
            #pragma unroll
            for (int i = 0; i < 4; ++i)
                #pragma unroll
                for (int j = 0; j < 4; ++j)
                    acc[i][j] = __builtin_amdgcn_mfma_f32_16x16x32_bf16(
                                    af[i], bfr[j], acc[i][j], 0, 0, 0);
        }
        __syncthreads();   // drains vmcnt(0)+lgkmcnt(0): t+1 staged, buf free
        buf ^= 1;
    }

    // ---- epilogue (identical to r0) ----
    const int row4 = (lane >> 4) << 2;
    #pragma unroll
    for (int i = 0; i < 4; ++i) {
        #pragma unroll
        for (int r = 0; r < 4; ++r) {
            int m = m0 + (wy << 6) + (i << 4) + row4 + r;
            #pragma unroll
            for (int j = 0; j < 4; ++j) {
                int n = n0 + (wx << 6) + (j << 4) + lm;
                float v = acc[i][j][r];
                if (MODE == 0) {
                    ((bf16_t*)outp)[(size_t)m * ldo + n] = (bf16_t)(v + bias[m]);
                } else if (MODE == 1) {
                    ((bf16_t*)outp)[(size_t)m * ldo + n] = (bf16_t)(v + bias[n]);
                } else {
                    ((float*)outp)[(size_t)m * ldo + n] =
                        v + bias[n] + res[(size_t)m * ldo + n];
                }
            }
        }
    }
}

// ---------------- GLU combine: v = za * sigmoid(zg), bf16 ---------------------
__global__ __launch_bounds__(256)
void glu_combine_kernel(const bf16_t* __restrict__ z, bf16_t* __restrict__ v)
{
    int i = blockIdx.x * 256 + threadIdx.x;       // one thread = 8 elements
    int m = i >> 7, n8 = (i & 127) << 3;
    const bf16_t* zp = z + (size_t)m * 2048 + n8;
    bf16x8 za = *(const bf16x8*)zp;
    bf16x8 zg = *(const bf16x8*)(zp + 1024);
    bf16x8 o;
    #pragma unroll
    for (int e = 0; e < 8; ++e) {
        float a = (float)za[e], gg = (float)zg[e];
        o[e] = (bf16_t)(a / (1.f + expf(-gg)));
    }
    *(bf16x8*)(v + (size_t)m * 1024 + n8) = o;
}

// ---------------- genV + genTP merged (block-uniform branch) ------------------
__global__ __launch_bounds__(64)
void genVTP_kernel(const float* __restrict__ log_dt, const float* __restrict__ lar,
                   const float* __restrict__ aim, const float* __restrict__ Cp,
                   const float* __restrict__ dskip,
                   bf16_t* __restrict__ V, bf16_t* __restrict__ TP)
{
    const int tid = threadIdx.x;
    if (blockIdx.x < DD / 2) {
        const int h = blockIdx.x * 2 + (tid >> 5);
        const int n = tid & 31;
        const float dt = expf(log_dt[h]);
        const float ardt = -expf(lar[h * NM + n]) * dt;
        const float aidt = aim[h * NM + n] * dt;
        float sn, cs;
        sincosf(aidt, &sn, &cs);
        float er = expf(ardt);
        float wr = er * cs, wi = er * sn;
        float inv = 1.f / fmaf(wr, wr, wi * wi);
        float vr = wr * inv, vi = -wi * inv;      // w^-1
        sincosf(63.f * aidt, &sn, &cs);
        er = expf(63.f * ardt);
        float pr = er * cs, pi = er * sn;         // w^63
        bf16_t* rowr = V + ((size_t)h * 64 + 2 * n) * 64;
        bf16_t* rowi = rowr + 64;
        #pragma unroll
        for (int c8 = 0; c8 < 8; ++c8) {
            bf16x8 rr, ri;
            #pragma unroll
            for (int e = 0; e < 8; ++e) {
                rr[e] = (bf16_t)pr; ri[e] = (bf16_t)pi;
                float t = fmaf(pr, vr, -pi * vi);
                pi = fmaf(pr, vi, pi * vr);
                pr = t;
            }
            *(bf16x8*)(rowr + c8 * 8) = rr;
            *(bf16x8*)(rowi + c8 * 8) = ri;
        }
        return;
    }
    // ---- TP branch ----
    __shared__ float ardt_s[NM], aidt_s[NM], cr_s[NM], ci_s[NM], K_s[CL];
    const int h = blockIdx.x - DD / 2;
    const float dt = expf(log_dt[h]);
    if (tid < NM) {
        int n = tid;
        float ar = -expf(lar[h * NM + n]);
        float ai = aim[h * NM + n];
        float sn, cs;
        sincosf(ai * dt, &sn, &cs);
        float er = expf(ar * dt);
        float wrr = er * cs, wii = er * sn;
        float Crr = Cp[(h * NM + n) * 2 + 0];
        float Cii = Cp[(h * NM + n) * 2 + 1];
        float nr = fmaf(Crr, wrr - 1.f, -Cii * wii);
        float ni = fmaf(Crr, wii, Cii * (wrr - 1.f));
        float inv = 2.f / fmaf(ar, ar, ai * ai);
        cr_s[n] = fmaf(nr, ar, ni * ai) * inv;
        ci_s[n] = fmaf(ni, ar, -nr * ai) * inv;
        ardt_s[n] = ar * dt;
        aidt_s[n] = ai * dt;
    }
    __syncthreads();
    {   // K[d] = sum_n cr*Re(w^d) - ci*Im(w^d);  K[0] += D_skip
        float d = (float)tid;
        float kv = (tid == 0) ? dskip[h] : 0.f;
        #pragma unroll 8
        for (int n = 0; n < NM; ++n) {
            float sn, cs;
            sincosf(aidt_s[n] * d, &sn, &cs);
            float e = expf(ardt_s[n] * d);
            kv = fmaf(cr_s[n], e * cs, kv);
            kv = fmaf(-ci_s[n], e * sn, kv);
        }
        K_s[tid] = kv;
    }
    __syncthreads();
    const int i = tid;
    bf16_t* row = TP + ((size_t)h * CL + i) * 128;
    #pragma unroll
    for (int c8 = 0; c8 < 8; ++c8) {
        bf16x8 v;
        #pragma unroll
        for (int e = 0; e < 8; ++e) {
            int l = c8 * 8 + e;
            v[e] = (l <= i) ? (bf16_t)K_s[i - l] : (bf16_t)0.f;
        }
        *(bf16x8*)(row + c8 * 8) = v;
    }
    const float fi = (float)(i + 1);
    #pragma unroll
    for (int c8 = 0; c8 < 8; ++c8) {
        bf16x8 v;
        #pragma unroll
        for (int q = 0; q < 4; ++q) {
            int n = c8 * 4 + q;
            float sn, cs;
            sincosf(aidt_s[n] * fi, &sn, &cs);
            float e = expf(ardt_s[n] * fi);
            float Wr = e * cs, Wi = e * sn;
            v[2 * q]     = (bf16_t)(fmaf(cr_s[n], Wr, -ci_s[n] * Wi));
            v[2 * q + 1] = (bf16_t)(-fmaf(cr_s[n], Wi, ci_s[n] * Wr));
        }
        *(bf16x8*)(row + 64 + c8 * 8) = v;
    }
}

// ---------------- fused SSM: S=U@V^T -> scan (LDS) -> Y=[U|Sc]@TP^T, gelu -----
__global__ __launch_bounds__(256)
void ssm_fused_kernel(const bf16_t* __restrict__ u_ch, const bf16_t* __restrict__ V,
                      const bf16_t* __restrict__ TP,
                      const float* __restrict__ log_dt, const float* __restrict__ lar,
                      const float* __restrict__ aim, bf16_t* __restrict__ y_bi)
{
    __shared__ float  Sbc_s[128 * 64];
    __shared__ bf16_t Sc_s[128 * 64];
    const int h = blockIdx.x;
    const int tid = threadIdx.x;
    const int lane = tid & 63, w = tid >> 6;
    const int lm = lane & 15, ks = (lane >> 4) << 3;
    const bf16_t* U   = u_ch + (size_t)h * 8192;  // [128 batch][64 l]
    const bf16_t* Vh  = V    + (size_t)h * 4096;  // [64 comp][64 l]
    const bf16_t* TPh = TP   + (size_t)h * 8192;  // [64 i][128 k]

    bf16x8 af_u[2][2];
    #pragma unroll
    for (int im = 0; im < 2; ++im)
        #pragma unroll
        for (int kk = 0; kk < 2; ++kk)
            af_u[im][kk] = *(const bf16x8*)(U + (((w << 1) + im) * 16 + lm) * 64
                                            + kk * 32 + ks);

    // ---- G1: chunk-local end states ----
    f32x4 acc1[2][4] = {};
    #pragma unroll
    for (int kk = 0; kk < 2; ++kk) {
        bf16x8 bfr[4];
        #pragma unroll
        for (int jn = 0; jn < 4; ++jn)
            bfr[jn] = *(const bf16x8*)(Vh + (jn * 16 + lm) * 64 + kk * 32 + ks);
        #pragma unroll
        for (int im = 0; im < 2; ++im)
            #pragma unroll
            for (int jn = 0; jn < 4; ++jn)
                acc1[im][jn] = __builtin_amdgcn_mfma_f32_16x16x32_bf16(
                                   af_u[im][kk], bfr[jn], acc1[im][jn], 0, 0, 0);
    }
    const int r4 = (lane >> 4) << 2;
    #pragma unroll
    for (int im = 0; im < 2; ++im)
        #pragma unroll
        for (int jn = 0; jn < 4; ++jn)
            #pragma unroll
            for (int r = 0; r < 4; ++r)
                Sbc_s[(((w << 1) + im) * 16 + r4 + r) * 64 + jn * 16 + lm]
                    = acc1[im][jn][r];
    __syncthreads();

    // ---- scan over chunks: thread t -> (b = t>>5, n = t&31) ----
    {
        const int b = tid >> 5, n = tid & 31;
        const float dtv = expf(log_dt[h]);
        const float ardt = -expf(lar[h * NM + n]) * dtv;
        const float aidt = aim[h * NM + n] * dtv;
        float sn, cs;
        sincosf(64.f * aidt, &sn, &cs);
        float er = expf(64.f * ardt);
        const float gr = er * cs, gi = er * sn;   // w^CL
        float sr = 0.f, si = 0.f;
        for (int c = 0; c < NCH; ++c) {
            int idx = (b * 16 + c) * 64 + 2 * n;
            float lr = Sbc_s[idx], li = Sbc_s[idx + 1];
            Sc_s[idx]     = (bf16_t)sr;           // carry-in state for chunk c
            Sc_s[idx + 1] = (bf16_t)si;
            float t0 = fmaf(gr, sr, fmaf(-gi, si, lr));
            si = fmaf(gr, si, fmaf(gi, sr, li));
            sr = t0;
        }
    }
    __syncthreads();

    // ---- G3: Y = [U | Sc] @ TP^T, gelu ----
    f32x4 acc2[2][4] = {};
    #pragma unroll
    for (int kk = 0; kk < 4; ++kk) {
        bf16x8 af[2], bfr[4];
        #pragma unroll
        for (int im = 0; im < 2; ++im) {
            if (kk < 2)
                af[im] = af_u[im][kk];
            else
                af[im] = *(bf16x8*)&Sc_s[(((w << 1) + im) * 16 + lm) * 64
                                         + (kk - 2) * 32 + ks];
        }
        #pragma unroll
        for (int jn = 0; jn < 4; ++jn)
            bfr[jn] = *(const bf16x8*)(TPh + (jn * 16 + lm) * 128 + kk * 32 + ks);
        #pragma unroll
        for (int im = 0; im < 2; ++im)
            #pragma unroll
            for (int jn = 0; jn < 4; ++jn)
                acc2[im][jn] = __builtin_amdgcn_mfma_f32_16x16x32_bf16(
                                   af[im], bfr[jn], acc2[im][jn], 0, 0, 0);
    }
    bf16_t* out = y_bi + (size_t)h * 8192;        // [128 batch][64 i]
    #pragma unroll
    for (int im = 0; im < 2; ++im)
        #pragma unroll
        for (int jn = 0; jn < 4; ++jn)
            #pragma unroll
            for (int r = 0; r < 4; ++r) {
                int batch = ((w << 1) + im) * 16 + r4 + r;
                int i = jn * 16 + lm;
                out[batch * 64 + i] = (bf16_t)gelu_f(acc2[im][jn][r]);
            }
}

// ---------------- 64x64 bf16 tile transpose: dst[c][r] = src[r][c] ------------
__global__ __launch_bounds__(256)
void transpose_kernel(const bf16_t* __restrict__ src, bf16_t* __restrict__ dst,
                      int src_rows, int src_cols)
{
    __shared__ unsigned short tile[64][68];
    const int tid = threadIdx.x;
    const int c0 = blockIdx.x << 6, r0 = blockIdx.y << 6;
    const int r = tid >> 4, c4 = (tid & 15) << 2;
    #pragma unroll
    for (int p = 0; p < 4; ++p) {
        int rr = p * 16 + r;
        ushort4 v = *(const ushort4*)((const unsigned short*)src +
                                      (size_t)(r0 + rr) * src_cols + c0 + c4);
        *(ushort4*)&tile[rr][c4] = v;
    }
    __syncthreads();
    #pragma unroll
    for (int p = 0; p < 4; ++p) {
        int rr = p * 16 + r;                      // dst-row-local (src col)
        ushort4 v;
        v.x = tile[c4 + 0][rr];
        v.y = tile[c4 + 1][rr];
        v.z = tile[c4 + 2][rr];
        v.w = tile[c4 + 3][rr];
        *(ushort4*)((unsigned short*)dst + (size_t)(c0 + rr) * src_rows + r0 + c4) = v;
    }
}

extern "C" void kernel_launch(void* const* d_in, const int* in_sizes, int n_in,
                              void* d_out, int out_size, void* d_ws, size_t ws_size,
                              hipStream_t stream)
{
    (void)in_sizes; (void)n_in; (void)out_size; (void)ws_size;
    const float* x      = (const float*)d_in[0];
    const float* in_W   = (const float*)d_in[1];
    const float* in_b   = (const float*)d_in[2];
    const float* log_dt = (const float*)d_in[3];
    const float* Cp     = (const float*)d_in[4];
    const float* lar    = (const float*)d_in[5];
    const float* aim    = (const float*)d_in[6];
    const float* dsk    = (const float*)d_in[7];
    const float* gluW   = (const float*)d_in[8];
    const float* glub   = (const float*)d_in[9];
    const float* outW   = (const float*)d_in[10];
    const float* outb   = (const float*)d_in[11];

    // ws layout (56.6 MiB peak):
    //  [0,16M):  xb -> TP (after in-proj) -> y_tok (after ssm) -> vb (after z GEMM)
    //  [16,24M): V  -> [16,48M): z (after ssm; clobbers V + u_ch, both dead)
    //  [32,48M): u_ch (bf16, channel-major)
    //  [48M..):  wbin 2M | wbglu 4M | wbout 2M
    // d_out: y_bi bf16 (16M) -> final output
    char* ws = (char*)d_ws;
    bf16_t* xb    = (bf16_t*)(ws);
    bf16_t* TP    = (bf16_t*)(ws);
    bf16_t* y_tok = (bf16_t*)(ws);
    bf16_t* vb    = (bf16_t*)(ws);
    bf16_t* V     = (bf16_t*)(ws + 16777216);
    bf16_t* z     = (bf16_t*)(ws + 16777216);
    bf16_t* u_ch  = (bf16_t*)(ws + 33554432);
    bf16_t* wbin  = (bf16_t*)(ws + 50331648);
    bf16_t* wbglu = (bf16_t*)(ws + 52428800);
    bf16_t* wbout = (bf16_t*)(ws + 56623104);
    bf16_t* y_bi  = (bf16_t*)d_out;

    f2b_all_kernel<<<dim3(12288), dim3(256), 0, stream>>>(
        x, xb, in_W, wbin, gluW, wbglu, outW, wbout);

    // in-proj, channel-major output: u_ch[h][token]
    gemm_db_kernel<0><<<dim3(NTOK / 128, DD / 128), dim3(256), 0, stream>>>(
        wbin, xb, in_b, nullptr, u_ch, NTOK);

    // SSM: param tables, then fused per-channel (G1 -> scan -> G3)
    genVTP_kernel<<<dim3(DD / 2 + DD), dim3(64), 0, stream>>>(
        log_dt, lar, aim, Cp, dsk, V, TP);
    ssm_fused_kernel<<<dim3(DD), dim3(256), 0, stream>>>(
        u_ch, V, TP, log_dt, lar, aim, y_bi);

    // back to token-major, then GLU (plain N=2048 GEMM + combine) + out-proj
    transpose_kernel<<<dim3(NTOK / 64, DD / 64), dim3(256), 0, stream>>>(y_bi, y_tok, DD, NTOK);
    gemm_db_kernel<1><<<dim3(2048 / 128, NTOK / 128), dim3(256), 0, stream>>>(
        y_tok, wbglu, glub, nullptr, z, 2048);
    glu_combine_kernel<<<dim3(NTOK * DD / 8 / 256), dim3(256), 0, stream>>>(z, vb);
    gemm_db_kernel<2><<<dim3(DD / 128, NTOK / 128), dim3(256), 0, stream>>>(
        vb, wbout, outb, x, d_out, DD);
}

// Round 5
// 258.383 us; speedup vs baseline: 1.3297x; 1.1255x over previous
//
#include <hip/hip_runtime.h>
#include <math.h>

#define BB 8
#define LL 1024
#define DD 1024
#define KD 1024   // GEMM K depth (token-space GEMMs)
#define NM 32     // complex modes per channel
#define NCH 16    // chunks over L
#define CL 64     // chunk length (NCH*CL == LL)
#define NTOK (BB * LL)

typedef __bf16 bf16_t;
typedef __bf16 bf16x8 __attribute__((ext_vector_type(8)));
typedef __bf16 bf16x4 __attribute__((ext_vector_type(4)));
typedef float  f32x4  __attribute__((ext_vector_type(4)));

__device__ __forceinline__ float gelu_f(float z)
{
    float t = fmaf(0.044715f * z * z, z, z);
    return z / (1.f + expf(-1.5957691216f * t));
}

// ---------------- fused fp32 -> bf16 converts (x, in_W, gluW, outW) -----------
__global__ __launch_bounds__(256)
void f2b_all_kernel(const float* __restrict__ x,    bf16_t* __restrict__ xb,
                    const float* __restrict__ w0,   bf16_t* __restrict__ d0,
                    const float* __restrict__ w1,   bf16_t* __restrict__ d1,
                    const float* __restrict__ w2,   bf16_t* __restrict__ d2)
{
    int b = blockIdx.x;
    const float* s; bf16_t* d; int base;
    if (b < 8192)       { s = x;  d = xb; base = b; }
    else if (b < 9216)  { s = w0; d = d0; base = b - 8192; }
    else if (b < 11264) { s = w1; d = d1; base = b - 9216; }
    else                { s = w2; d = d2; base = b - 11264; }
    int i = (base * 256 + threadIdx.x) * 4;
    float4 f = *(const float4*)(s + i);
    bf16x4 o = { (bf16_t)f.x, (bf16_t)f.y, (bf16_t)f.z, (bf16_t)f.w };
    *(bf16x4*)(d + i) = o;
}

// =============================================================================
// 128x128 GEMM, BK=64, 4 waves (2x2), 256 threads -- verified r4 structure:
//  (a) granule-XOR LDS swizzle (conflicts 4.19M -> 0, verified r1/r4)
//  (b) minimum 2-phase double-buffer (stage(t+1) before compute(t))
// MODE 0: bf16 out = acc + bias[m]            (in-proj, channel-major out)
// MODE 1: bf16 out = acc + bias[n]            (GLU z)
// MODE 2: f32  out = acc + bias[n] + res[m,n] (out-proj + residual)
// =============================================================================
#define GLL(gp, lp) __builtin_amdgcn_global_load_lds( \
    (const __attribute__((address_space(1))) void*)(gp), \
    (__attribute__((address_space(3))) void*)(lp), 16, 0, 0)

// one K-tile: A 128 rows x 64 cols + B 128 rows x 64 cols, 4+4 loads/thread
__device__ __forceinline__ void stage_tile(const bf16_t* __restrict__ Ag,
                                           const bf16_t* __restrict__ Bg,
                                           bf16_t* Asb, bf16_t* Bsb, int tid)
{
    #pragma unroll
    for (int p = 0; p < 4; ++p) {
        int e = p * 256 + tid;                    // 0..1023 (128 rows x 8 gran)
        int row = e >> 3, sc = ((e & 7) ^ (row & 7)) << 3;
        GLL(Ag + (size_t)row * KD + sc, Asb + e * 8);
    }
    #pragma unroll
    for (int p = 0; p < 4; ++p) {
        int e = p * 256 + tid;
        int row = e >> 3, sc = ((e & 7) ^ (row & 7)) << 3;
        GLL(Bg + (size_t)row * KD + sc, Bsb + e * 8);
    }
}

template<int MODE>
__global__ __launch_bounds__(256, 2)
void gemm_db_kernel(const bf16_t* __restrict__ A, const bf16_t* __restrict__ B,
                    const float* __restrict__ bias, const float* __restrict__ res,
                    void* __restrict__ outp, int ldo)
{
    __shared__ bf16_t As[2][128 * 64];
    __shared__ bf16_t Bs[2][128 * 64];
    const int tid = threadIdx.x;
    const int lane = tid & 63, w = tid >> 6;
    const int wy = w >> 1, wx = w & 1;
    const int m0 = blockIdx.y << 7, n0 = blockIdx.x << 7;
    const bf16_t* Ag = A + (size_t)m0 * KD;
    const bf16_t* Bg = B + (size_t)n0 * KD;
    f32x4 acc[4][4] = {};
    const int lm = lane & 15;
    const int qq = lane >> 4;                     // quarter-wave index

    stage_tile(Ag, Bg, As[0], Bs[0], tid);
    __syncthreads();

    int buf = 0;
    #pragma unroll 1
    for (int t = 0; t < 16; ++t) {
        if (t + 1 < 16)
            stage_tile(Ag + (t + 1) * 64, Bg + (t + 1) * 64,
                       As[buf ^ 1], Bs[buf ^ 1], tid);
        #pragma unroll
        for (int kk = 0; kk < 2; ++kk) {
            bf16x8 af[4], bfr[4];
            const int g = (kk << 2) + qq;         // logical 16B granule 0..7
            #pragma unroll
            for (int i = 0; i < 4; ++i) {
                int row = (wy << 6) + (i << 4) + lm;
                af[i] = *(const bf16x8*)&As[buf][row * 64 + ((g ^ (row & 7)) << 3)];
            }
            #pragma unroll
            for (int j = 0; j < 4; ++j) {
                int row = (wx << 6) + (j << 4) + lm;
                bfr[j] = *(const bf16x8*)&Bs[buf][row * 64 + ((g ^ (row & 7)) << 3)];
            }
            #pragma unroll
            for (int i = 0; i < 4; ++i)
                #pragma unroll
                for (int j = 0; j < 4; ++j)
                    acc[i][j] = __builtin_amdgcn_mfma_f32_16x16x32_bf16(
                                    af[i], bfr[j], acc[i][j], 0, 0, 0);
        }
        __syncthreads();   // drains vmcnt(0)+lgkmcnt(0): t+1 staged, buf free
        buf ^= 1;
    }

    // ---- epilogue ----
    const int row4 = (lane >> 4) << 2;
    #pragma unroll
    for (int i = 0; i < 4; ++i) {
        #pragma unroll
        for (int r = 0; r < 4; ++r) {
            int m = m0 + (wy << 6) + (i << 4) + row4 + r;
            #pragma unroll
            for (int j = 0; j < 4; ++j) {
                int n = n0 + (wx << 6) + (j << 4) + lm;
                float v = acc[i][j][r];
                if (MODE == 0) {
                    ((bf16_t*)outp)[(size_t)m * ldo + n] = (bf16_t)(v + bias[m]);
                } else if (MODE == 1) {
                    ((bf16_t*)outp)[(size_t)m * ldo + n] = (bf16_t)(v + bias[n]);
                } else {
                    ((float*)outp)[(size_t)m * ldo + n] =
                        v + bias[n] + res[(size_t)m * ldo + n];
                }
            }
        }
    }
}

// ---------------- GLU combine: v = za * sigmoid(zg), bf16 ---------------------
__global__ __launch_bounds__(256)
void glu_combine_kernel(const bf16_t* __restrict__ z, bf16_t* __restrict__ v)
{
    int i = blockIdx.x * 256 + threadIdx.x;       // one thread = 8 elements
    int m = i >> 7, n8 = (i & 127) << 3;
    const bf16_t* zp = z + (size_t)m * 2048 + n8;
    bf16x8 za = *(const bf16x8*)zp;
    bf16x8 zg = *(const bf16x8*)(zp + 1024);
    bf16x8 o;
    #pragma unroll
    for (int e = 0; e < 8; ++e) {
        float a = (float)za[e], gg = (float)zg[e];
        o[e] = (bf16_t)(a / (1.f + expf(-gg)));
    }
    *(bf16x8*)(v + (size_t)m * 1024 + n8) = o;
}

// ---------------- genV + genTP merged (block-uniform branch) ------------------
// TP branch rewritten (r5): per-(n,d) sincosf/expf (64x64 per channel, latency-
// bound at 8.7% VALUBusy / 73 us) replaced by a per-channel Vandermonde table
// E[d][n] = w_n^d built via complex recurrence -- 1 sincos+exp per thread
// (32x fewer transcendentals). Table in LDS, row stride 33 (bank-conflict-free
// cross-lane column reads). fp32 recurrence error over 32 steps << bf16 ulp.
__global__ __launch_bounds__(64)
void genVTP_kernel(const float* __restrict__ log_dt, const float* __restrict__ lar,
                   const float* __restrict__ aim, const float* __restrict__ Cp,
                   const float* __restrict__ dskip,
                   bf16_t* __restrict__ V, bf16_t* __restrict__ TP)
{
    const int tid = threadIdx.x;
    if (blockIdx.x < DD / 2) {
        const int h = blockIdx.x * 2 + (tid >> 5);
        const int n = tid & 31;
        const float dt = expf(log_dt[h]);
        const float ardt = -expf(lar[h * NM + n]) * dt;
        const float aidt = aim[h * NM + n] * dt;
        float sn, cs;
        sincosf(aidt, &sn, &cs);
        float er = expf(ardt);
        float wr = er * cs, wi = er * sn;
        float inv = 1.f / fmaf(wr, wr, wi * wi);
        float vr = wr * inv, vi = -wi * inv;      // w^-1
        sincosf(63.f * aidt, &sn, &cs);
        er = expf(63.f * ardt);
        float pr = er * cs, pi = er * sn;         // w^63
        bf16_t* rowr = V + ((size_t)h * 64 + 2 * n) * 64;
        bf16_t* rowi = rowr + 64;
        #pragma unroll
        for (int c8 = 0; c8 < 8; ++c8) {
            bf16x8 rr, ri;
            #pragma unroll
            for (int e = 0; e < 8; ++e) {
                rr[e] = (bf16_t)pr; ri[e] = (bf16_t)pi;
                float t = fmaf(pr, vr, -pi * vi);
                pi = fmaf(pr, vi, pi * vr);
                pr = t;
            }
            *(bf16x8*)(rowr + c8 * 8) = rr;
            *(bf16x8*)(rowi + c8 * 8) = ri;
        }
        return;
    }
    // ---- TP branch ----
    __shared__ float cr_s[NM], ci_s[NM], K_s[CL];
    __shared__ float wr_s[NM], wi_s[NM], ardt_s[NM], aidt_s[NM];
    __shared__ float er_s[65 * 33], ei_s[65 * 33];   // E[d][n] = w_n^d, pad 33
    const int h = blockIdx.x - DD / 2;
    if (tid < NM) {
        int n = tid;
        const float dt = expf(log_dt[h]);
        float ar = -expf(lar[h * NM + n]);
        float ai = aim[h * NM + n];
        float sn, cs;
        sincosf(ai * dt, &sn, &cs);
        float er = expf(ar * dt);
        float wrr = er * cs, wii = er * sn;
        float Crr = Cp[(h * NM + n) * 2 + 0];
        float Cii = Cp[(h * NM + n) * 2 + 1];
        float nr = fmaf(Crr, wrr - 1.f, -Cii * wii);
        float ni = fmaf(Crr, wii, Cii * (wrr - 1.f));
        float inv = 2.f / fmaf(ar, ar, ai * ai);
        cr_s[n] = fmaf(nr, ar, ni * ai) * inv;
        ci_s[n] = fmaf(ni, ar, -nr * ai) * inv;
        wr_s[n] = wrr;  wi_s[n] = wii;
        ardt_s[n] = ar * dt;
        aidt_s[n] = ai * dt;
        er_s[n] = 1.f;  ei_s[n] = 0.f;            // row d = 0
    }
    __syncthreads();
    {   // table rows d = 1..64: half 0 -> 1..32, half 1 -> 33..64
        const int n = tid & 31;
        const int s = 1 + (tid >> 5) * 32;
        float sn, cs;
        sincosf(aidt_s[n] * (float)s, &sn, &cs);
        float e0 = expf(ardt_s[n] * (float)s);
        float pr = e0 * cs, pi = e0 * sn;
        const float wr = wr_s[n], wi = wi_s[n];
        int base = s * 33 + n;
        #pragma unroll
        for (int j = 0; j < 32; ++j) {
            er_s[base] = pr;  ei_s[base] = pi;
            float t0 = fmaf(pr, wr, -pi * wi);
            pi = fmaf(pr, wi, pi * wr);
            pr = t0;
            base += 33;
        }
    }
    __syncthreads();
    {   // K[d] = sum_n cr*Re(w^d) - ci*Im(w^d);  K[0] += D_skip
        const int d = tid;
        float kv = (d == 0) ? dskip[h] : 0.f;
        #pragma unroll
        for (int n = 0; n < NM; ++n) {
            kv = fmaf(cr_s[n], er_s[d * 33 + n], kv);
            kv = fmaf(-ci_s[n], ei_s[d * 33 + n], kv);
        }
        K_s[d] = kv;
    }
    __syncthreads();
    const int i = tid;
    bf16_t* row = TP + ((size_t)h * CL + i) * 128;
    #pragma unroll
    for (int c8 = 0; c8 < 8; ++c8) {
        bf16x8 v;
        #pragma unroll
        for (int e = 0; e < 8; ++e) {
            int l = c8 * 8 + e;
            v[e] = (l <= i) ? (bf16_t)K_s[i - l] : (bf16_t)0.f;
        }
        *(bf16x8*)(row + c8 * 8) = v;
    }
    #pragma unroll
    for (int c8 = 0; c8 < 8; ++c8) {
        bf16x8 v;
        #pragma unroll
        for (int q = 0; q < 4; ++q) {
            int n = c8 * 4 + q;
            float Wr = er_s[(i + 1) * 33 + n];    // w_n^(i+1) from table
            float Wi = ei_s[(i + 1) * 33 + n];
            v[2 * q]     = (bf16_t)(fmaf(cr_s[n], Wr, -ci_s[n] * Wi));
            v[2 * q + 1] = (bf16_t)(-fmaf(cr_s[n], Wi, ci_s[n] * Wr));
        }
        *(bf16x8*)(row + 64 + c8 * 8) = v;
    }
}

// ---------------- fused SSM: S=U@V^T -> scan (LDS) -> Y=[U|Sc]@TP^T, gelu -----
__global__ __launch_bounds__(256)
void ssm_fused_kernel(const bf16_t* __restrict__ u_ch, const bf16_t* __restrict__ V,
                      const bf16_t* __restrict__ TP,
                      const float* __restrict__ log_dt, const float* __restrict__ lar,
                      const float* __restrict__ aim, bf16_t* __restrict__ y_bi)
{
    __shared__ float  Sbc_s[128 * 64];
    __shared__ bf16_t Sc_s[128 * 64];
    const int h = blockIdx.x;
    const int tid = threadIdx.x;
    const int lane = tid & 63, w = tid >> 6;
    const int lm = lane & 15, ks = (lane >> 4) << 3;
    const bf16_t* U   = u_ch + (size_t)h * 8192;  // [128 batch][64 l]
    const bf16_t* Vh  = V    + (size_t)h * 4096;  // [64 comp][64 l]
    const bf16_t* TPh = TP   + (size_t)h * 8192;  // [64 i][128 k]

    bf16x8 af_u[2][2];
    #pragma unroll
    for (int im = 0; im < 2; ++im)
        #pragma unroll
        for (int kk = 0; kk < 2; ++kk)
            af_u[im][kk] = *(const bf16x8*)(U + (((w << 1) + im) * 16 + lm) * 64
                                            + kk * 32 + ks);

    // ---- G1: chunk-local end states ----
    f32x4 acc1[2][4] = {};
    #pragma unroll
    for (int kk = 0; kk < 2; ++kk) {
        bf16x8 bfr[4];
        #pragma unroll
        for (int jn = 0; jn < 4; ++jn)
            bfr[jn] = *(const bf16x8*)(Vh + (jn * 16 + lm) * 64 + kk * 32 + ks);
        #pragma unroll
        for (int im = 0; im < 2; ++im)
            #pragma unroll
            for (int jn = 0; jn < 4; ++jn)
                acc1[im][jn] = __builtin_amdgcn_mfma_f32_16x16x32_bf16(
                                   af_u[im][kk], bfr[jn], acc1[im][jn], 0, 0, 0);
    }
    const int r4 = (lane >> 4) << 2;
    #pragma unroll
    for (int im = 0; im < 2; ++im)
        #pragma unroll
        for (int jn = 0; jn < 4; ++jn)
            #pragma unroll
            for (int r = 0; r < 4; ++r)
                Sbc_s[(((w << 1) + im) * 16 + r4 + r) * 64 + jn * 16 + lm]
                    = acc1[im][jn][r];
    __syncthreads();

    // ---- scan over chunks: thread t -> (b = t>>5, n = t&31) ----
    {
        const int b = tid >> 5, n = tid & 31;
        const float dtv = expf(log_dt[h]);
        const float ardt = -expf(lar[h * NM + n]) * dtv;
        const float aidt = aim[h * NM + n] * dtv;
        float sn, cs;
        sincosf(64.f * aidt, &sn, &cs);
        float er = expf(64.f * ardt);
        const float gr = er * cs, gi = er * sn;   // w^CL
        float sr = 0.f, si = 0.f;
        for (int c = 0; c < NCH; ++c) {
            int idx = (b * 16 + c) * 64 + 2 * n;
            float lr = Sbc_s[idx], li = Sbc_s[idx + 1];
            Sc_s[idx]     = (bf16_t)sr;           // carry-in state for chunk c
            Sc_s[idx + 1] = (bf16_t)si;
            float t0 = fmaf(gr, sr, fmaf(-gi, si, lr));
            si = fmaf(gr, si, fmaf(gi, sr, li));
            sr = t0;
        }
    }
    __syncthreads();

    // ---- G3: Y = [U | Sc] @ TP^T, gelu ----
    f32x4 acc2[2][4] = {};
    #pragma unroll
    for (int kk = 0; kk < 4; ++kk) {
        bf16x8 af[2], bfr[4];
        #pragma unroll
        for (int im = 0; im < 2; ++im) {
            if (kk < 2)
                af[im] = af_u[im][kk];
            else
                af[im] = *(bf16x8*)&Sc_s[(((w << 1) + im) * 16 + lm) * 64
                                         + (kk - 2) * 32 + ks];
        }
        #pragma unroll
        for (int jn = 0; jn < 4; ++jn)
            bfr[jn] = *(const bf16x8*)(TPh + (jn * 16 + lm) * 128 + kk * 32 + ks);
        #pragma unroll
        for (int im = 0; im < 2; ++im)
            #pragma unroll
            for (int jn = 0; jn < 4; ++jn)
                acc2[im][jn] = __builtin_amdgcn_mfma_f32_16x16x32_bf16(
                                   af[im], bfr[jn], acc2[im][jn], 0, 0, 0);
    }
    bf16_t* out = y_bi + (size_t)h * 8192;        // [128 batch][64 i]
    #pragma unroll
    for (int im = 0; im < 2; ++im)
        #pragma unroll
        for (int jn = 0; jn < 4; ++jn)
            #pragma unroll
            for (int r = 0; r < 4; ++r) {
                int batch = ((w << 1) + im) * 16 + r4 + r;
                int i = jn * 16 + lm;
                out[batch * 64 + i] = (bf16_t)gelu_f(acc2[im][jn][r]);
            }
}

// ---------------- 64x64 bf16 tile transpose: dst[c][r] = src[r][c] ------------
__global__ __launch_bounds__(256)
void transpose_kernel(const bf16_t* __restrict__ src, bf16_t* __restrict__ dst,
                      int src_rows, int src_cols)
{
    __shared__ unsigned short tile[64][68];
    const int tid = threadIdx.x;
    const int c0 = blockIdx.x << 6, r0 = blockIdx.y << 6;
    const int r = tid >> 4, c4 = (tid & 15) << 2;
    #pragma unroll
    for (int p = 0; p < 4; ++p) {
        int rr = p * 16 + r;
        ushort4 v = *(const ushort4*)((const unsigned short*)src +
                                      (size_t)(r0 + rr) * src_cols + c0 + c4);
        *(ushort4*)&tile[rr][c4] = v;
    }
    __syncthreads();
    #pragma unroll
    for (int p = 0; p < 4; ++p) {
        int rr = p * 16 + r;                      // dst-row-local (src col)
        ushort4 v;
        v.x = tile[c4 + 0][rr];
        v.y = tile[c4 + 1][rr];
        v.z = tile[c4 + 2][rr];
        v.w = tile[c4 + 3][rr];
        *(ushort4*)((unsigned short*)dst + (size_t)(c0 + rr) * src_rows + r0 + c4) = v;
    }
}

extern "C" void kernel_launch(void* const* d_in, const int* in_sizes, int n_in,
                              void* d_out, int out_size, void* d_ws, size_t ws_size,
                              hipStream_t stream)
{
    (void)in_sizes; (void)n_in; (void)out_size; (void)ws_size;
    const float* x      = (const float*)d_in[0];
    const float* in_W   = (const float*)d_in[1];
    const float* in_b   = (const float*)d_in[2];
    const float* log_dt = (const float*)d_in[3];
    const float* Cp     = (const float*)d_in[4];
    const float* lar    = (const float*)d_in[5];
    const float* aim    = (const float*)d_in[6];
    const float* dsk    = (const float*)d_in[7];
    const float* gluW   = (const float*)d_in[8];
    const float* glub   = (const float*)d_in[9];
    const float* outW   = (const float*)d_in[10];
    const float* outb   = (const float*)d_in[11];

    // ws layout (56.6 MiB peak):
    //  [0,16M):  xb -> TP (after in-proj) -> y_tok (after ssm) -> vb (after z GEMM)
    //  [16,24M): V  -> [16,48M): z (after ssm; clobbers V + u_ch, both dead)
    //  [32,48M): u_ch (bf16, channel-major)
    //  [48M..):  wbin 2M | wbglu 4M | wbout 2M
    // d_out: y_bi bf16 (16M) -> final output
    char* ws = (char*)d_ws;
    bf16_t* xb    = (bf16_t*)(ws);
    bf16_t* TP    = (bf16_t*)(ws);
    bf16_t* y_tok = (bf16_t*)(ws);
    bf16_t* vb    = (bf16_t*)(ws);
    bf16_t* V     = (bf16_t*)(ws + 16777216);
    bf16_t* z     = (bf16_t*)(ws + 16777216);
    bf16_t* u_ch  = (bf16_t*)(ws + 33554432);
    bf16_t* wbin  = (bf16_t*)(ws + 50331648);
    bf16_t* wbglu = (bf16_t*)(ws + 52428800);
    bf16_t* wbout = (bf16_t*)(ws + 56623104);
    bf16_t* y_bi  = (bf16_t*)d_out;

    f2b_all_kernel<<<dim3(12288), dim3(256), 0, stream>>>(
        x, xb, in_W, wbin, gluW, wbglu, outW, wbout);

    // in-proj, channel-major output: u_ch[h][token]
    gemm_db_kernel<0><<<dim3(NTOK / 128, DD / 128), dim3(256), 0, stream>>>(
        wbin, xb, in_b, nullptr, u_ch, NTOK);

    // SSM: param tables, then fused per-channel (G1 -> scan -> G3)
    genVTP_kernel<<<dim3(DD / 2 + DD), dim3(64), 0, stream>>>(
        log_dt, lar, aim, Cp, dsk, V, TP);
    ssm_fused_kernel<<<dim3(DD), dim3(256), 0, stream>>>(
        u_ch, V, TP, log_dt, lar, aim, y_bi);

    // back to token-major, then GLU (plain N=2048 GEMM + combine) + out-proj
    transpose_kernel<<<dim3(NTOK / 64, DD / 64), dim3(256), 0, stream>>>(y_bi, y_tok, DD, NTOK);
    gemm_db_kernel<1><<<dim3(2048 / 128, NTOK / 128), dim3(256), 0, stream>>>(
        y_tok, wbglu, glub, nullptr, z, 2048);
    glu_combine_kernel<<<dim3(NTOK * DD / 8 / 256), dim3(256), 0, stream>>>(z, vb);
    gemm_db_kernel<2><<<dim3(DD / 128, NTOK / 128), dim3(256), 0, stream>>>(
        vb, wbout, outb, x, d_out, DD);
}